// Round 4
// baseline (739.315 us; speedup 1.0000x reference)
//
#include <hip/hip_runtime.h>

#define N_NODES 100000
#define N_EDGES 1600000
#define D 64

// ---------- bucketed CSR-free build parameters ----------
#define TILE_N 64          // nodes per bucket (= src>>6)
#define NBUK 1563          // ceil(100000/64)
#define BLKA 196           // pass-A blocks
#define EPB 8192           // edges per pass-A block (256 thr x 8 x int4)
#define NT (NBUK * BLKA)   // 306,348 ghist entries
#define NCH 300            // ceil(NT/1024) scan chunks

// ---- ws layout (4-byte units), ~14.0 MB (proven ws >= 20,400,640 B) ----
#define WS_GHIST   0                 // [NT] per-(bucket,block) counts -> scanned bases
#define WS_PART    306432            // [384] chunk partials
#define WS_TPAIRS  306816            // int2[1600000]: ((src&63)<<17|dst, val) bucket-sorted
                                     // byte off 1,227,264 -> 8B aligned

// ---------------- pass A: per-(bucket,block) histogram ----------------
__global__ __launch_bounds__(256) void k_bucket_hist(
    const int* __restrict__ esrc, int* __restrict__ ghist)
{
    __shared__ int h[NBUK];
    int t = threadIdx.x;
    for (int j = t; j < NBUK; j += 256) h[j] = 0;
    __syncthreads();
    int base = blockIdx.x * EPB;
    #pragma unroll
    for (int i = 0; i < 8; ++i) {
        int e0 = base + i * 1024 + t * 4;
        if (e0 < N_EDGES) {                  // N_EDGES%4==0 -> whole int4 valid
            int4 s4 = *(const int4*)(esrc + e0);
            atomicAdd(&h[s4.x >> 6], 1);
            atomicAdd(&h[s4.y >> 6], 1);
            atomicAdd(&h[s4.z >> 6], 1);
            atomicAdd(&h[s4.w >> 6], 1);
        }
    }
    __syncthreads();
    // bucket-major layout: ghist[j*BLKA + blk] (1.2MB array, L2-resident)
    for (int j = t; j < NBUK; j += 256) ghist[j * BLKA + blockIdx.x] = h[j];
}

// ---------------- scan of ghist (2-kernel redundant-partial pattern) ----------------
__global__ __launch_bounds__(1024) void k_ghist_scan1(
    const int* __restrict__ ghist, int* __restrict__ partial)
{
    __shared__ int sred[16];
    int t = threadIdx.x;
    int idx = blockIdx.x * 1024 + t;
    int v = (idx < NT) ? ghist[idx] : 0;
    #pragma unroll
    for (int off = 32; off; off >>= 1) v += __shfl_down(v, off, 64);
    if ((t & 63) == 0) sred[t >> 6] = v;
    __syncthreads();
    if (t < 16) {
        int w = sred[t];
        #pragma unroll
        for (int off = 8; off; off >>= 1) w += __shfl_down(w, off, 16);
        if (t == 0) partial[blockIdx.x] = w;
    }
}

__global__ __launch_bounds__(1024) void k_ghist_scan2(
    int* __restrict__ ghist, const int* __restrict__ partial)
{
    __shared__ int red1[16];
    __shared__ int wsum[16];
    __shared__ int bc;
    int t = threadIdx.x;
    int lane = t & 63, wid = t >> 6;

    // base = sum of partials of chunks before this one (redundant per block)
    int pv = (t < NCH) ? partial[t] : 0;
    int a1 = (t < (int)blockIdx.x) ? pv : 0;
    #pragma unroll
    for (int off = 32; off; off >>= 1) a1 += __shfl_down(a1, off, 64);
    if (lane == 0) red1[wid] = a1;
    __syncthreads();
    if (t < 16) {
        int w = red1[t];
        #pragma unroll
        for (int off = 8; off; off >>= 1) w += __shfl_down(w, off, 16);
        if (t == 0) bc = w;
    }
    __syncthreads();

    // exclusive scan of this chunk, in place
    int idx = blockIdx.x * 1024 + t;
    int v = (idx < NT) ? ghist[idx] : 0;
    int s = v;
    #pragma unroll
    for (int off = 1; off < 64; off <<= 1) {
        int y = __shfl_up(s, off, 64);
        if (lane >= off) s += y;
    }
    if (lane == 63) wsum[wid] = s;
    __syncthreads();
    if (t < 16) {
        int w = wsum[t];
        #pragma unroll
        for (int off = 1; off < 16; off <<= 1) {
            int y = __shfl_up(w, off, 16);
            if (t >= off) w += y;
        }
        wsum[t] = w;
    }
    __syncthreads();
    int prefix = wid ? wsum[wid - 1] : 0;
    if (idx < NT) ghist[idx] = bc + prefix + s - v;
}

// ---------------- pass A scatter: bucket-partition edges ----------------
// Each (bucket, block) owns a contiguous output window; LDS cursor
// atomic-returns order within it. 8B packed record: ((src&63)<<17 | dst, val)
// (dst < 2^17 since N_NODES = 100000). Window runs are sequential -> writes
// combine in L2 (open-line set 1563*64B = 100KB/block, fits per-XCD L2).
__global__ __launch_bounds__(256) void k_scatter(
    const int* __restrict__ esrc, const int* __restrict__ edst,
    const float* __restrict__ eval_, const int* __restrict__ ghist,
    int2* __restrict__ tpairs)
{
    __shared__ int base[NBUK];
    int t = threadIdx.x;
    for (int j = t; j < NBUK; j += 256) base[j] = ghist[j * BLKA + blockIdx.x];
    __syncthreads();
    int eb = blockIdx.x * EPB;
    #pragma unroll
    for (int i = 0; i < 8; ++i) {
        int e0 = eb + i * 1024 + t * 4;
        if (e0 < N_EDGES) {
            int4 s4 = *(const int4*)(esrc + e0);
            int4 d4 = *(const int4*)(edst + e0);
            float4 v4 = *(const float4*)(eval_ + e0);
            int p0 = atomicAdd(&base[s4.x >> 6], 1);
            int p1 = atomicAdd(&base[s4.y >> 6], 1);
            int p2 = atomicAdd(&base[s4.z >> 6], 1);
            int p3 = atomicAdd(&base[s4.w >> 6], 1);
            tpairs[p0] = make_int2(((s4.x & 63) << 17) | d4.x, __float_as_int(v4.x));
            tpairs[p1] = make_int2(((s4.y & 63) << 17) | d4.y, __float_as_int(v4.y));
            tpairs[p2] = make_int2(((s4.z & 63) << 17) | d4.z, __float_as_int(v4.z));
            tpairs[p3] = make_int2(((s4.w & 63) << 17) | d4.w, __float_as_int(v4.w));
        }
    }
}

// ---------------- bucketed aggregation: rep = agg + eps*x ----------------
// Replaces k_build_csr + k_gather. One block per 64-node bucket; rep tile
// (64x64 f32 = 16KB) accumulated in LDS via ds_add_f32 (fire-and-forget, no
// waitcnt -> fully hidden under the x-gather miss wall).
// Load layout: 4 subs x 16 lanes; lane owns cols {f4,f4+16,f4+32,f4+48} of
// each edge's x row -> per dword-instr each sub reads ONE 64B line (4 lines/
// instr, 16 instrs in flight = 64 lines/wave — identical line-MLP to R3's
// proven 66us gather). LDS bank spread: strided cols + per-row rotation
// (col+n)&63 -> ~2-way conflicts.
__global__ __launch_bounds__(256) void k_tile_gather(
    const float* __restrict__ x, const int2* __restrict__ tpairs,
    const int* __restrict__ ghist, const float* __restrict__ epsilon,
    float* __restrict__ rep)
{
    __shared__ float tile[TILE_N * D];   // 16 KB
    int b = blockIdx.x, t = threadIdx.x;
    {
        float4* t4 = (float4*)tile;
        #pragma unroll
        for (int i = 0; i < 4; ++i)
            t4[t + i * 256] = make_float4(0.f, 0.f, 0.f, 0.f);
    }
    __syncthreads();

    int begin = ghist[b * BLKA];
    int end   = (b + 1 < NBUK) ? ghist[(b + 1) * BLKA] : N_EDGES;

    int wv = t >> 6, lane = t & 63;
    int sub = lane >> 4, f4 = lane & 15;

    for (int j = begin + wv * 16; j < end; j += 4 * 16) {
        int2 p[4];
        #pragma unroll
        for (int u = 0; u < 4; ++u) {
            int e = j + u * 4 + sub;
            p[u] = (e < end) ? tpairs[e] : make_int2(0, 0);
        }
        float a[4][4];
        #pragma unroll
        for (int u = 0; u < 4; ++u) {
            int dst = p[u].x & 0x1FFFF;
            #pragma unroll
            for (int c = 0; c < 4; ++c)
                a[u][c] = x[dst * D + f4 + 16 * c];  // masked: row 0, vv=0
        }
        #pragma unroll
        for (int u = 0; u < 4; ++u) {
            float vv = __int_as_float(p[u].y);
            int n = p[u].x >> 17;
            #pragma unroll
            for (int c = 0; c < 4; ++c) {
                int col = (f4 + 16 * c + n) & 63;    // rotation vs banks
                atomicAdd(&tile[n * D + col], vv * a[u][c]);
            }
        }
    }
    __syncthreads();

    // epilogue: rep[node] = tile (un-rotated) + eps * x[node]
    float eps = epsilon[0];
    int n0 = b * TILE_N;
    const float4* x4 = (const float4*)x;
    #pragma unroll
    for (int i = 0; i < 4; ++i) {
        int f = t + i * 256;          // 0..1023 float4 slots
        int n = f >> 4, c4 = f & 15;
        int node = n0 + n;
        if (node < N_NODES) {
            float r0 = tile[n * D + ((c4 * 4 + 0 + n) & 63)];
            float r1 = tile[n * D + ((c4 * 4 + 1 + n) & 63)];
            float r2 = tile[n * D + ((c4 * 4 + 2 + n) & 63)];
            float r3 = tile[n * D + ((c4 * 4 + 3 + n) & 63)];
            float4 xv = x4[(size_t)node * 16 + c4];
            ((float4*)rep)[(size_t)node * 16 + c4] =
                make_float4(r0 + eps * xv.x, r1 + eps * xv.y,
                            r2 + eps * xv.z, r3 + eps * xv.w);
        }
    }
}

// ---------------- out = rep @ W + bias ----------------
#define GEMM_TM 64
__global__ __launch_bounds__(256) void k_gemm(
    const float* __restrict__ rep, const float* __restrict__ weight,
    const float* __restrict__ bias, float* __restrict__ out)
{
    __shared__ float rep_s[GEMM_TM * 68];
    __shared__ float Ws[D * D];
    int t = threadIdx.x;
    {
        const float4* w4 = (const float4*)weight;
        float4* s4 = (float4*)Ws;
        #pragma unroll
        for (int i = 0; i < (D * D / 4) / 256; ++i)
            s4[t + i * 256] = w4[t + i * 256];
    }
    int row0 = blockIdx.x * GEMM_TM;
    {
        const float4* r4 = (const float4*)rep;
        #pragma unroll
        for (int i = 0; i < 4; ++i) {
            int f = t + i * 256;
            int rr = f >> 4, kk4 = f & 15;
            float4 v = (row0 + rr < N_NODES) ? r4[(size_t)(row0 + rr) * 16 + kk4]
                                             : make_float4(0.f, 0.f, 0.f, 0.f);
            rep_s[rr * 68 + kk4 * 4 + 0] = v.x;
            rep_s[rr * 68 + kk4 * 4 + 1] = v.y;
            rep_s[rr * 68 + kk4 * 4 + 2] = v.z;
            rep_s[rr * 68 + kk4 * 4 + 3] = v.w;
        }
    }
    __syncthreads();

    int tx = t & 15, ty = t >> 4;
    float4 b4 = ((const float4*)bias)[tx];
    float acc[4][4];
    #pragma unroll
    for (int i = 0; i < 4; ++i) {
        acc[i][0] = b4.x; acc[i][1] = b4.y; acc[i][2] = b4.z; acc[i][3] = b4.w;
    }
    #pragma unroll 4
    for (int k4 = 0; k4 < 16; ++k4) {
        float4 rv[4];
        #pragma unroll
        for (int i = 0; i < 4; ++i)
            rv[i] = *(const float4*)&rep_s[(ty * 4 + i) * 68 + k4 * 4];
        #pragma unroll
        for (int kk = 0; kk < 4; ++kk) {
            float4 wv = *(const float4*)&Ws[(k4 * 4 + kk) * D + tx * 4];
            #pragma unroll
            for (int i = 0; i < 4; ++i) {
                float r = ((const float*)&rv[i])[kk];
                acc[i][0] += r * wv.x;
                acc[i][1] += r * wv.y;
                acc[i][2] += r * wv.z;
                acc[i][3] += r * wv.w;
            }
        }
    }
    #pragma unroll
    for (int i = 0; i < 4; ++i) {
        int row = row0 + ty * 4 + i;
        if (row < N_NODES)
            *(float4*)&out[(size_t)row * D + tx * 4] =
                make_float4(acc[i][0], acc[i][1], acc[i][2], acc[i][3]);
    }
}

extern "C" void kernel_launch(void* const* d_in, const int* in_sizes, int n_in,
                              void* d_out, int out_size, void* d_ws, size_t ws_size,
                              hipStream_t stream) {
    const float* x    = (const float*)d_in[0];
    const int*   esrc = (const int*)  d_in[1];
    const int*   edst = (const int*)  d_in[2];
    const float* ev   = (const float*)d_in[3];
    const float* w    = (const float*)d_in[4];
    const float* eps  = (const float*)d_in[5];
    const float* bias = (const float*)d_in[6];

    float* out = (float*)d_out;
    float* rep = out + (size_t)N_NODES * D;

    int* ws      = (int*)d_ws;
    int* ghist   = ws + WS_GHIST;
    int* partial = ws + WS_PART;
    int2* tpairs = (int2*)(ws + WS_TPAIRS);

    k_bucket_hist<<<BLKA, 256, 0, stream>>>(esrc, ghist);
    k_ghist_scan1<<<NCH, 1024, 0, stream>>>(ghist, partial);
    k_ghist_scan2<<<NCH, 1024, 0, stream>>>(ghist, partial);
    k_scatter<<<BLKA, 256, 0, stream>>>(esrc, edst, ev, ghist, tpairs);
    k_tile_gather<<<NBUK, 256, 0, stream>>>(x, tpairs, ghist, eps, rep);
    k_gemm<<<(N_NODES + GEMM_TM - 1) / GEMM_TM, 256, 0, stream>>>(rep, w, bias, out);
}

// Round 6
// 222.530 us; speedup vs baseline: 3.3223x; 3.3223x over previous
//
#include <hip/hip_runtime.h>

#define N_NODES 100000
#define N_EDGES 1600000
#define D 64

// ---------- counting-sort CSR parameters ----------
// R5 post-mortem: LDS-atomic phases are issue-rate bound per CU; need >=3
// blocks/CU. 782 columns/buckets -> 3.05 blocks/CU everywhere.
#define NB 782            // buckets = src>>7 (128 nodes each)
#define BLKA 782          // hist/scatter columns (blocks)
#define EPB 2048          // edges per column (782*2048 = 1,601,536 >= 1.6M)
#define NT (NB * BLKA)    // 611,524 ghist entries
#define NCH 598           // ceil(NT/1024) scan chunks

// ---- ws layout (4-byte units), end = 3,912,256 ints = 15.65 MB (ws >= 20,400,640 B) ----
#define WS_GHIST   0                 // [611,584 padded] per-(bucket,col) counts -> scanned bases
#define WS_PART    611584            // [640 padded] chunk partials
#define WS_ROWPTR  612224            // [100,032] row_ptr (+pad)
#define WS_PAIRS   712256            // int2[1,600,000] final CSR payload (packed key)
// tpairs (int2[1.6M], bucket-sorted payload, packed (src&127)<<17|dst) lives in
// the rep region of d_out: fully consumed by k_build before k_gather writes rep.

// ---------------- pass A: per-(bucket,column) histogram ----------------
// 782 blocks (3.05/CU) so per-CU LDS-atomic issue aggregates across blocks.
__global__ __launch_bounds__(256) void k_hist(
    const int* __restrict__ esrc, int* __restrict__ ghist)
{
    __shared__ int h[NB];
    int t = threadIdx.x;
    for (int j = t; j < NB; j += 256) h[j] = 0;
    __syncthreads();
    int base = blockIdx.x * EPB;
    #pragma unroll
    for (int i = 0; i < 2; ++i) {
        int e0 = base + i * 1024 + t * 4;
        if (e0 < N_EDGES) {                  // N_EDGES%4==0 -> whole int4 valid
            int4 s4 = *(const int4*)(esrc + e0);
            atomicAdd(&h[s4.x >> 7], 1);
            atomicAdd(&h[s4.y >> 7], 1);
            atomicAdd(&h[s4.z >> 7], 1);
            atomicAdd(&h[s4.w >> 7], 1);
        }
    }
    __syncthreads();
    // bucket-major layout: ghist[j*BLKA + blk] (2.4MB, L2-resident)
    for (int j = t; j < NB; j += 256) ghist[j * BLKA + blockIdx.x] = h[j];
}

// ---------------- scan of ghist (2-kernel redundant-partial pattern) ----------------
__global__ __launch_bounds__(1024) void k_scan1(
    const int* __restrict__ ghist, int* __restrict__ partial)
{
    __shared__ int sred[16];
    int t = threadIdx.x;
    int idx = blockIdx.x * 1024 + t;
    int v = (idx < NT) ? ghist[idx] : 0;
    #pragma unroll
    for (int off = 32; off; off >>= 1) v += __shfl_down(v, off, 64);
    if ((t & 63) == 0) sred[t >> 6] = v;
    __syncthreads();
    if (t < 16) {
        int w = sred[t];
        #pragma unroll
        for (int off = 8; off; off >>= 1) w += __shfl_down(w, off, 16);
        if (t == 0) partial[blockIdx.x] = w;
    }
}

__global__ __launch_bounds__(1024) void k_scan2(
    int* __restrict__ ghist, const int* __restrict__ partial)
{
    __shared__ int red1[16];
    __shared__ int wsum[16];
    __shared__ int bc;
    int t = threadIdx.x;
    int lane = t & 63, wid = t >> 6;

    // chunk base = sum of earlier chunks' partials (redundant per block)
    int pv = (t < NCH) ? partial[t] : 0;
    int a1 = (t < (int)blockIdx.x) ? pv : 0;
    #pragma unroll
    for (int off = 32; off; off >>= 1) a1 += __shfl_down(a1, off, 64);
    if (lane == 0) red1[wid] = a1;
    __syncthreads();
    if (t < 16) {
        int w = red1[t];
        #pragma unroll
        for (int off = 8; off; off >>= 1) w += __shfl_down(w, off, 16);
        if (t == 0) bc = w;
    }
    __syncthreads();

    // exclusive scan of this 1024-entry chunk, in place
    int idx = blockIdx.x * 1024 + t;
    int v = (idx < NT) ? ghist[idx] : 0;
    int s = v;
    #pragma unroll
    for (int off = 1; off < 64; off <<= 1) {
        int y = __shfl_up(s, off, 64);
        if (lane >= off) s += y;
    }
    if (lane == 63) wsum[wid] = s;
    __syncthreads();
    if (t < 16) {
        int w = wsum[t];
        #pragma unroll
        for (int off = 1; off < 16; off <<= 1) {
            int y = __shfl_up(w, off, 16);
            if (t >= off) w += y;
        }
        wsum[t] = w;
    }
    __syncthreads();
    int prefix = wid ? wsum[wid - 1] : 0;
    if (idx < NT) ghist[idx] = bc + prefix + s - v;
}

// ---------------- pass A scatter: bucket-partition edges ----------------
// Packed record: ((src&127)<<17 | dst, val) — keys array eliminated
// (saves 12.8 MB of scattered traffic vs R3). dst < 2^17 since N=100000.
__global__ __launch_bounds__(256) void k_scatter(
    const int* __restrict__ esrc, const int* __restrict__ edst,
    const float* __restrict__ eval_, const int* __restrict__ ghist,
    int2* __restrict__ tpairs)
{
    __shared__ int base[NB];
    int t = threadIdx.x;
    for (int j = t; j < NB; j += 256) base[j] = ghist[j * BLKA + blockIdx.x];
    __syncthreads();
    int eb = blockIdx.x * EPB;
    #pragma unroll
    for (int i = 0; i < 2; ++i) {
        int e0 = eb + i * 1024 + t * 4;
        if (e0 < N_EDGES) {
            int4 s4 = *(const int4*)(esrc + e0);
            int4 d4 = *(const int4*)(edst + e0);
            float4 v4 = *(const float4*)(eval_ + e0);
            int p0 = atomicAdd(&base[s4.x >> 7], 1);
            int p1 = atomicAdd(&base[s4.y >> 7], 1);
            int p2 = atomicAdd(&base[s4.z >> 7], 1);
            int p3 = atomicAdd(&base[s4.w >> 7], 1);
            tpairs[p0] = make_int2(((s4.x & 127) << 17) | d4.x, __float_as_int(v4.x));
            tpairs[p1] = make_int2(((s4.y & 127) << 17) | d4.y, __float_as_int(v4.y));
            tpairs[p2] = make_int2(((s4.z & 127) << 17) | d4.z, __float_as_int(v4.z));
            tpairs[p3] = make_int2(((s4.w & 127) << 17) | d4.w, __float_as_int(v4.w));
        }
    }
}

// ---------------- pass B: per-bucket CSR finalize ----------------
// One 256-thr block per 128-node bucket (~2048 edges): LDS 128-bin hist+scan
// -> row_ptr + in-bucket ranks; scatter into a 16KB L2-resident window.
// 782 blocks = 3.05/CU (R5 fix: aggregate LDS-atomic issue rate).
__global__ __launch_bounds__(256) void k_build(
    const int2* __restrict__ tpairs, const int* __restrict__ ghist,
    int* __restrict__ row_ptr, int2* __restrict__ pairs)
{
    __shared__ int hist[128], cursor[128], wsum2[2];
    int b = blockIdx.x, t = threadIdx.x;
    int s_begin = ghist[b * BLKA];
    int s_end = (b + 1 < NB) ? ghist[(b + 1) * BLKA] : N_EDGES;
    if (t < 128) hist[t] = 0;
    __syncthreads();
    #pragma unroll 4
    for (int pos = s_begin + t; pos < s_end; pos += 256)
        atomicAdd(&hist[(tpairs[pos].x >> 17) & 127], 1);
    __syncthreads();
    // exclusive scan of 128 bins (threads 0..127, 2 waves)
    int lane = t & 63, wid = t >> 6;
    int v = 0, s = 0;
    if (t < 128) {
        v = hist[t]; s = v;
        #pragma unroll
        for (int off = 1; off < 64; off <<= 1) {
            int y = __shfl_up(s, off, 64);
            if (lane >= off) s += y;
        }
        if (lane == 63) wsum2[wid] = s;
    }
    __syncthreads();
    if (t == 0) { int x0 = wsum2[0]; wsum2[0] = 0; wsum2[1] = x0; }
    __syncthreads();
    if (t < 128) {
        int excl = wsum2[wid] + s - v;
        cursor[t] = excl;
        int node = (b << 7) + t;
        if (node <= N_NODES) row_ptr[node] = s_begin + excl;
    }
    __syncthreads();
    #pragma unroll 4
    for (int pos = s_begin + t; pos < s_end; pos += 256) {
        int2 pv = tpairs[pos];
        int k = (pv.x >> 17) & 127;
        int p = atomicAdd(&cursor[k], 1);
        pairs[s_begin + p] = pv;     // keep packed; gather masks dst
    }
}

// ---------------- aggregation: rep = agg + eps*x (R1/R3-proven 66us wall) ----------------
// 4 edges x 16 lanes per wave, lane loads float4 (1KB/VMEM-instr); single
// masked 16-edge step; 2048 blocks = 32 waves/CU. Pinned at ~3.4TB/s L2-miss
// service rate — do NOT trade occupancy here (R2 lesson).
#define GATHER_BLOCKS 2048

__global__ __launch_bounds__(256) void k_gather(
    const float* __restrict__ x, const int* __restrict__ row_ptr,
    const int2* __restrict__ pairs, const float* __restrict__ epsilon,
    float* __restrict__ rep)
{
    int w = (blockIdx.x * 256 + threadIdx.x) >> 6;   // global wave id
    int nw = gridDim.x * 4;                          // 8192
    int lane = threadIdx.x & 63;
    int sub = lane >> 4;                             // edge slot 0..3
    int f4 = lane & 15;                              // float4 index in row
    float eps = epsilon[0];
    const float4* x4 = (const float4*)x;

    int r0 = (int)((long long)w * N_NODES / nw);
    int r1 = (int)((long long)(w + 1) * N_NODES / nw);

    for (int row = r0; row < r1; ++row) {
        int start = __builtin_amdgcn_readfirstlane(row_ptr[row]);
        int end   = __builtin_amdgcn_readfirstlane(row_ptr[row + 1]);
        float4 acc = make_float4(0.f, 0.f, 0.f, 0.f);
        for (int j = start; j < end; j += 16) {
            int2 p[4];
            #pragma unroll
            for (int u = 0; u < 4; ++u) {
                int e = j + u * 4 + sub;
                p[u] = (e < end) ? pairs[e] : make_int2(0, 0);
            }
            float4 a[4];
            #pragma unroll
            for (int u = 0; u < 4; ++u)
                a[u] = x4[(size_t)(p[u].x & 0x1FFFF) * 16 + f4];  // masked: row 0, vv=0
            #pragma unroll
            for (int u = 0; u < 4; ++u) {
                float vv = __int_as_float(p[u].y);
                acc.x += vv * a[u].x; acc.y += vv * a[u].y;
                acc.z += vv * a[u].z; acc.w += vv * a[u].w;
            }
        }
        #pragma unroll
        for (int off = 16; off <= 32; off <<= 1) {
            acc.x += __shfl_xor(acc.x, off, 64);
            acc.y += __shfl_xor(acc.y, off, 64);
            acc.z += __shfl_xor(acc.z, off, 64);
            acc.w += __shfl_xor(acc.w, off, 64);
        }
        if (sub == 0) {
            float4 xv = x4[(size_t)row * 16 + f4];
            float4 o = make_float4(acc.x + eps * xv.x, acc.y + eps * xv.y,
                                   acc.z + eps * xv.z, acc.w + eps * xv.w);
            ((float4*)rep)[(size_t)row * 16 + f4] = o;
        }
    }
}

// ---------------- out = rep @ W + bias ----------------
#define GEMM_TM 64
__global__ __launch_bounds__(256) void k_gemm(
    const float* __restrict__ rep, const float* __restrict__ weight,
    const float* __restrict__ bias, float* __restrict__ out)
{
    __shared__ float rep_s[GEMM_TM * 68];
    __shared__ float Ws[D * D];
    int t = threadIdx.x;
    {
        const float4* w4 = (const float4*)weight;
        float4* s4 = (float4*)Ws;
        #pragma unroll
        for (int i = 0; i < (D * D / 4) / 256; ++i)
            s4[t + i * 256] = w4[t + i * 256];
    }
    int row0 = blockIdx.x * GEMM_TM;
    {
        const float4* r4 = (const float4*)rep;
        #pragma unroll
        for (int i = 0; i < 4; ++i) {
            int f = t + i * 256;
            int rr = f >> 4, kk4 = f & 15;
            float4 v = (row0 + rr < N_NODES) ? r4[(size_t)(row0 + rr) * 16 + kk4]
                                             : make_float4(0.f, 0.f, 0.f, 0.f);
            rep_s[rr * 68 + kk4 * 4 + 0] = v.x;
            rep_s[rr * 68 + kk4 * 4 + 1] = v.y;
            rep_s[rr * 68 + kk4 * 4 + 2] = v.z;
            rep_s[rr * 68 + kk4 * 4 + 3] = v.w;
        }
    }
    __syncthreads();

    int tx = t & 15, ty = t >> 4;
    float4 b4 = ((const float4*)bias)[tx];
    float acc[4][4];
    #pragma unroll
    for (int i = 0; i < 4; ++i) {
        acc[i][0] = b4.x; acc[i][1] = b4.y; acc[i][2] = b4.z; acc[i][3] = b4.w;
    }
    #pragma unroll 4
    for (int k4 = 0; k4 < 16; ++k4) {
        float4 rv[4];
        #pragma unroll
        for (int i = 0; i < 4; ++i)
            rv[i] = *(const float4*)&rep_s[(ty * 4 + i) * 68 + k4 * 4];
        #pragma unroll
        for (int kk = 0; kk < 4; ++kk) {
            float4 wv = *(const float4*)&Ws[(k4 * 4 + kk) * D + tx * 4];
            #pragma unroll
            for (int i = 0; i < 4; ++i) {
                float r = ((const float*)&rv[i])[kk];
                acc[i][0] += r * wv.x;
                acc[i][1] += r * wv.y;
                acc[i][2] += r * wv.z;
                acc[i][3] += r * wv.w;
            }
        }
    }
    #pragma unroll
    for (int i = 0; i < 4; ++i) {
        int row = row0 + ty * 4 + i;
        if (row < N_NODES)
            *(float4*)&out[(size_t)row * D + tx * 4] =
                make_float4(acc[i][0], acc[i][1], acc[i][2], acc[i][3]);
    }
}

extern "C" void kernel_launch(void* const* d_in, const int* in_sizes, int n_in,
                              void* d_out, int out_size, void* d_ws, size_t ws_size,
                              hipStream_t stream) {
    const float* x    = (const float*)d_in[0];
    const int*   esrc = (const int*)  d_in[1];
    const int*   edst = (const int*)  d_in[2];
    const float* ev   = (const float*)d_in[3];
    const float* w    = (const float*)d_in[4];
    const float* eps  = (const float*)d_in[5];
    const float* bias = (const float*)d_in[6];

    float* out = (float*)d_out;
    float* rep = out + (size_t)N_NODES * D;

    int* ws      = (int*)d_ws;
    int* ghist   = ws + WS_GHIST;
    int* partial = ws + WS_PART;
    int* row_ptr = ws + WS_ROWPTR;
    int2* pairs  = (int2*)(ws + WS_PAIRS);
    int2* tpairs = (int2*)rep;   // consumed by k_build before k_gather writes rep

    k_hist<<<BLKA, 256, 0, stream>>>(esrc, ghist);
    k_scan1<<<NCH, 1024, 0, stream>>>(ghist, partial);
    k_scan2<<<NCH, 1024, 0, stream>>>(ghist, partial);
    k_scatter<<<BLKA, 256, 0, stream>>>(esrc, edst, ev, ghist, tpairs);
    k_build<<<NB, 256, 0, stream>>>(tpairs, ghist, row_ptr, pairs);
    k_gather<<<GATHER_BLOCKS, 256, 0, stream>>>(x, row_ptr, pairs, eps, rep);
    k_gemm<<<(N_NODES + GEMM_TM - 1) / GEMM_TM, 256, 0, stream>>>(rep, w, bias, out);
}

// Round 7
// 199.880 us; speedup vs baseline: 3.6988x; 1.1133x over previous
//
#include <hip/hip_runtime.h>
#include <hip/hip_fp16.h>

#define N_NODES 100000
#define N_EDGES 1600000
#define D 64

// ---------- counting-sort CSR parameters ----------
// R6 post-mortem: CSR floor = LDS-atomic rate (~3.6 cy/lane-atomic/CU, R4) +
// scatter write granularity + scan size. NB=BLKA=391: NT=153K (4x smaller
// scan than R6), scatter windows 10.5 edges (84B vs R6's 21B).
#define NB 391            // buckets = src>>8 (256 nodes each)
#define BLKA 391          // hist/scatter columns (blocks)
#define EPB 4096          // edges per column (391*4096 = 1,601,536 >= 1.6M)
#define NT (NB * BLKA)    // 152,881 ghist entries
#define NCH 150           // ceil(NT/1024) scan chunks

// ---- ws layout (4-byte units), end = 5,053,184 ints = 20,212,736 B (ws >= 20,400,640) ----
#define WS_GHIST   0                 // [152,896 pad] per-(bucket,col) counts -> scanned bases
#define WS_PART    152896            // [256 pad] chunk partials
#define WS_ROWPTR  153152            // [100,032] row_ptr (+pad)
#define WS_PAIRSU  253184            // uint[1,600,000] packed CSR: (dst<<15)|(fp16(val)>>1)
#define WS_XH      1853184           // fp16 x [100,000*64] = 3,200,000 ints (8B-aligned)
// tpairs (int2[1.6M], bucket-sorted, (src&255)<<17|dst) lives in the rep
// region of d_out: fully consumed by k_build before k_gather writes rep.

// ---------------- pass A: per-(bucket,column) histogram + x->fp16 ----------------
// fp16 conversion fused here (saves a dispatch): x ~ N(0,1), RNE rel-err 2^-11
// -> absmax impact ~0.01 vs threshold 0.525. Halves gather's random-row bytes
// AND doubles its L2 hit rate (footprint 25.6 -> 12.8 MB).
__global__ __launch_bounds__(256) void k_hist_cvt(
    const int* __restrict__ esrc, const float* __restrict__ x,
    int* __restrict__ ghist, uint2* __restrict__ xh2)
{
    __shared__ int h[NB];
    int t = threadIdx.x;
    for (int j = t; j < NB; j += 256) h[j] = 0;
    __syncthreads();
    int base = blockIdx.x * EPB;
    #pragma unroll
    for (int i = 0; i < 4; ++i) {
        int e0 = base + i * 1024 + t * 4;
        if (e0 < N_EDGES) {                  // N_EDGES%4==0 -> whole int4 valid
            int4 s4 = *(const int4*)(esrc + e0);
            atomicAdd(&h[s4.x >> 8], 1);
            atomicAdd(&h[s4.y >> 8], 1);
            atomicAdd(&h[s4.z >> 8], 1);
            atomicAdd(&h[s4.w >> 8], 1);
        }
    }
    // x -> fp16 slice (independent of hist; overlaps the LDS atomics)
    {
        const float4* x4 = (const float4*)x;
        #pragma unroll
        for (int i = 0; i < 16; ++i) {
            int f = blockIdx.x * 4096 + i * 256 + t;   // float4 index, 1.6M total
            if (f < N_NODES * (D / 4)) {
                float4 v = x4[f];
                uint2 o;
                o.x = (uint)__half_as_ushort(__float2half_rn(v.x)) |
                      ((uint)__half_as_ushort(__float2half_rn(v.y)) << 16);
                o.y = (uint)__half_as_ushort(__float2half_rn(v.z)) |
                      ((uint)__half_as_ushort(__float2half_rn(v.w)) << 16);
                xh2[f] = o;
            }
        }
    }
    __syncthreads();
    // bucket-major layout: ghist[j*BLKA + blk] (0.6MB, L2-resident)
    for (int j = t; j < NB; j += 256) ghist[j * BLKA + blockIdx.x] = h[j];
}

// ---------------- scan of ghist (2-kernel redundant-partial pattern) ----------------
__global__ __launch_bounds__(1024) void k_scan1(
    const int* __restrict__ ghist, int* __restrict__ partial)
{
    __shared__ int sred[16];
    int t = threadIdx.x;
    int idx = blockIdx.x * 1024 + t;
    int v = (idx < NT) ? ghist[idx] : 0;
    #pragma unroll
    for (int off = 32; off; off >>= 1) v += __shfl_down(v, off, 64);
    if ((t & 63) == 0) sred[t >> 6] = v;
    __syncthreads();
    if (t < 16) {
        int w = sred[t];
        #pragma unroll
        for (int off = 8; off; off >>= 1) w += __shfl_down(w, off, 16);
        if (t == 0) partial[blockIdx.x] = w;
    }
}

__global__ __launch_bounds__(1024) void k_scan2(
    int* __restrict__ ghist, const int* __restrict__ partial)
{
    __shared__ int red1[16];
    __shared__ int wsum[16];
    __shared__ int bc;
    int t = threadIdx.x;
    int lane = t & 63, wid = t >> 6;

    // chunk base = sum of earlier chunks' partials (redundant per block)
    int pv = (t < NCH) ? partial[t] : 0;
    int a1 = (t < (int)blockIdx.x) ? pv : 0;
    #pragma unroll
    for (int off = 32; off; off >>= 1) a1 += __shfl_down(a1, off, 64);
    if (lane == 0) red1[wid] = a1;
    __syncthreads();
    if (t < 16) {
        int w = red1[t];
        #pragma unroll
        for (int off = 8; off; off >>= 1) w += __shfl_down(w, off, 16);
        if (t == 0) bc = w;
    }
    __syncthreads();

    // exclusive scan of this 1024-entry chunk, in place
    int idx = blockIdx.x * 1024 + t;
    int v = (idx < NT) ? ghist[idx] : 0;
    int s = v;
    #pragma unroll
    for (int off = 1; off < 64; off <<= 1) {
        int y = __shfl_up(s, off, 64);
        if (lane >= off) s += y;
    }
    if (lane == 63) wsum[wid] = s;
    __syncthreads();
    if (t < 16) {
        int w = wsum[t];
        #pragma unroll
        for (int off = 1; off < 16; off <<= 1) {
            int y = __shfl_up(w, off, 16);
            if (t >= off) w += y;
        }
        wsum[t] = w;
    }
    __syncthreads();
    int prefix = wid ? wsum[wid - 1] : 0;
    if (idx < NT) ghist[idx] = bc + prefix + s - v;
}

// ---------------- pass A scatter: bucket-partition edges ----------------
// Window avg 10.5 edges (84B) -> ~1.2x line-touch amplification (R6: ~3x).
// Packed record: ((src&255)<<17 | dst, val); dst < 2^17.
__global__ __launch_bounds__(256) void k_scatter(
    const int* __restrict__ esrc, const int* __restrict__ edst,
    const float* __restrict__ eval_, const int* __restrict__ ghist,
    int2* __restrict__ tpairs)
{
    __shared__ int base[NB];
    int t = threadIdx.x;
    for (int j = t; j < NB; j += 256) base[j] = ghist[j * BLKA + blockIdx.x];
    __syncthreads();
    int eb = blockIdx.x * EPB;
    #pragma unroll
    for (int i = 0; i < 4; ++i) {
        int e0 = eb + i * 1024 + t * 4;
        if (e0 < N_EDGES) {
            int4 s4 = *(const int4*)(esrc + e0);
            int4 d4 = *(const int4*)(edst + e0);
            float4 v4 = *(const float4*)(eval_ + e0);
            int p0 = atomicAdd(&base[s4.x >> 8], 1);
            int p1 = atomicAdd(&base[s4.y >> 8], 1);
            int p2 = atomicAdd(&base[s4.z >> 8], 1);
            int p3 = atomicAdd(&base[s4.w >> 8], 1);
            tpairs[p0] = make_int2(((s4.x & 255) << 17) | d4.x, __float_as_int(v4.x));
            tpairs[p1] = make_int2(((s4.y & 255) << 17) | d4.y, __float_as_int(v4.y));
            tpairs[p2] = make_int2(((s4.z & 255) << 17) | d4.z, __float_as_int(v4.z));
            tpairs[p3] = make_int2(((s4.w & 255) << 17) | d4.w, __float_as_int(v4.w));
        }
    }
}

// ---------------- pass B: per-bucket CSR finalize ----------------
// One 256-thr block per 256-node bucket (~4.1K edges): LDS 256-bin hist+scan
// -> row_ptr + ranks; output packed to 4B/edge: (dst<<15) | (fp16(val)>>1)
// (sign+exp+9 mantissa bits kept -> val rel-err 2^-10).
__global__ __launch_bounds__(256) void k_build(
    const int2* __restrict__ tpairs, const int* __restrict__ ghist,
    int* __restrict__ row_ptr, unsigned int* __restrict__ pairsu)
{
    __shared__ int hist[256], cursor[256], wsum4[4];
    int b = blockIdx.x, t = threadIdx.x;
    int s_begin = ghist[b * BLKA];
    int s_end = (b + 1 < NB) ? ghist[(b + 1) * BLKA] : N_EDGES;
    hist[t] = 0;
    __syncthreads();
    #pragma unroll 4
    for (int pos = s_begin + t; pos < s_end; pos += 256)
        atomicAdd(&hist[(tpairs[pos].x >> 17) & 255], 1);
    __syncthreads();
    // exclusive scan of 256 bins
    int lane = t & 63, wid = t >> 6;
    int v = hist[t], s = v;
    #pragma unroll
    for (int off = 1; off < 64; off <<= 1) {
        int y = __shfl_up(s, off, 64);
        if (lane >= off) s += y;
    }
    if (lane == 63) wsum4[wid] = s;
    __syncthreads();
    if (t == 0) {
        int r = 0;
        #pragma unroll
        for (int k = 0; k < 4; ++k) { int w = wsum4[k]; wsum4[k] = r; r += w; }
    }
    __syncthreads();
    int excl = wsum4[wid] + s - v;
    cursor[t] = excl;
    int node = (b << 8) + t;
    if (node <= N_NODES) row_ptr[node] = s_begin + excl;
    __syncthreads();
    #pragma unroll 4
    for (int pos = s_begin + t; pos < s_end; pos += 256) {
        int2 pv = tpairs[pos];
        int k = (pv.x >> 17) & 255;
        int p = atomicAdd(&cursor[k], 1);
        unsigned int dst = (unsigned int)pv.x & 0x1FFFFu;
        unsigned int hb = (unsigned int)__half_as_ushort(
            __float2half_rn(__int_as_float(pv.y)));
        pairsu[s_begin + p] = (dst << 15) | (hb >> 1);
    }
}

// ---------------- aggregation: rep = agg + eps*x ----------------
// R1/R3 structure (4 edges x 16 lanes/wave, 2048 blocks = 32 waves/CU), now on
// fp16 x rows (128B: lane loads uint2 = 4 halfs) + 4B packed pairs. Halves the
// random-miss bytes AND doubles L2 hit rate. eps*x diagonal stays f32-exact.
#define GATHER_BLOCKS 2048

__global__ __launch_bounds__(256) void k_gather(
    const float* __restrict__ x, const uint2* __restrict__ xh2,
    const int* __restrict__ row_ptr, const unsigned int* __restrict__ pairsu,
    const float* __restrict__ epsilon, float* __restrict__ rep)
{
    int w = (blockIdx.x * 256 + threadIdx.x) >> 6;   // global wave id
    int nw = gridDim.x * 4;                          // 8192
    int lane = threadIdx.x & 63;
    int sub = lane >> 4;                             // edge slot 0..3
    int f4 = lane & 15;                              // 8B-chunk index in row
    float eps = epsilon[0];
    const float4* x4 = (const float4*)x;

    int r0 = (int)((long long)w * N_NODES / nw);
    int r1 = (int)((long long)(w + 1) * N_NODES / nw);

    for (int row = r0; row < r1; ++row) {
        int start = __builtin_amdgcn_readfirstlane(row_ptr[row]);
        int end   = __builtin_amdgcn_readfirstlane(row_ptr[row + 1]);
        float4 acc = make_float4(0.f, 0.f, 0.f, 0.f);
        for (int j = start; j < end; j += 16) {
            unsigned int pk[4];
            #pragma unroll
            for (int u = 0; u < 4; ++u) {
                int e = j + u * 4 + sub;
                pk[u] = (e < end) ? pairsu[e] : 0u;   // 0 -> dst 0, val 0
            }
            uint2 a[4];
            #pragma unroll
            for (int u = 0; u < 4; ++u)
                a[u] = xh2[(size_t)(pk[u] >> 15) * 16 + f4];
            #pragma unroll
            for (int u = 0; u < 4; ++u) {
                unsigned short hb = (unsigned short)((pk[u] & 0x7FFFu) << 1);
                float vv = __half2float(__ushort_as_half(hb));
                float2 f01 = __half22float2(*reinterpret_cast<const __half2*>(&a[u].x));
                float2 f23 = __half22float2(*reinterpret_cast<const __half2*>(&a[u].y));
                acc.x += vv * f01.x; acc.y += vv * f01.y;
                acc.z += vv * f23.x; acc.w += vv * f23.y;
            }
        }
        #pragma unroll
        for (int off = 16; off <= 32; off <<= 1) {
            acc.x += __shfl_xor(acc.x, off, 64);
            acc.y += __shfl_xor(acc.y, off, 64);
            acc.z += __shfl_xor(acc.z, off, 64);
            acc.w += __shfl_xor(acc.w, off, 64);
        }
        if (sub == 0) {
            float4 xv = x4[(size_t)row * 16 + f4];
            float4 o = make_float4(acc.x + eps * xv.x, acc.y + eps * xv.y,
                                   acc.z + eps * xv.z, acc.w + eps * xv.w);
            ((float4*)rep)[(size_t)row * 16 + f4] = o;
        }
    }
}

// ---------------- out = rep @ W + bias ----------------
#define GEMM_TM 64
__global__ __launch_bounds__(256) void k_gemm(
    const float* __restrict__ rep, const float* __restrict__ weight,
    const float* __restrict__ bias, float* __restrict__ out)
{
    __shared__ float rep_s[GEMM_TM * 68];
    __shared__ float Ws[D * D];
    int t = threadIdx.x;
    {
        const float4* w4 = (const float4*)weight;
        float4* s4 = (float4*)Ws;
        #pragma unroll
        for (int i = 0; i < (D * D / 4) / 256; ++i)
            s4[t + i * 256] = w4[t + i * 256];
    }
    int row0 = blockIdx.x * GEMM_TM;
    {
        const float4* r4 = (const float4*)rep;
        #pragma unroll
        for (int i = 0; i < 4; ++i) {
            int f = t + i * 256;
            int rr = f >> 4, kk4 = f & 15;
            float4 v = (row0 + rr < N_NODES) ? r4[(size_t)(row0 + rr) * 16 + kk4]
                                             : make_float4(0.f, 0.f, 0.f, 0.f);
            rep_s[rr * 68 + kk4 * 4 + 0] = v.x;
            rep_s[rr * 68 + kk4 * 4 + 1] = v.y;
            rep_s[rr * 68 + kk4 * 4 + 2] = v.z;
            rep_s[rr * 68 + kk4 * 4 + 3] = v.w;
        }
    }
    __syncthreads();

    int tx = t & 15, ty = t >> 4;
    float4 b4 = ((const float4*)bias)[tx];
    float acc[4][4];
    #pragma unroll
    for (int i = 0; i < 4; ++i) {
        acc[i][0] = b4.x; acc[i][1] = b4.y; acc[i][2] = b4.z; acc[i][3] = b4.w;
    }
    #pragma unroll 4
    for (int k4 = 0; k4 < 16; ++k4) {
        float4 rv[4];
        #pragma unroll
        for (int i = 0; i < 4; ++i)
            rv[i] = *(const float4*)&rep_s[(ty * 4 + i) * 68 + k4 * 4];
        #pragma unroll
        for (int kk = 0; kk < 4; ++kk) {
            float4 wv = *(const float4*)&Ws[(k4 * 4 + kk) * D + tx * 4];
            #pragma unroll
            for (int i = 0; i < 4; ++i) {
                float r = ((const float*)&rv[i])[kk];
                acc[i][0] += r * wv.x;
                acc[i][1] += r * wv.y;
                acc[i][2] += r * wv.z;
                acc[i][3] += r * wv.w;
            }
        }
    }
    #pragma unroll
    for (int i = 0; i < 4; ++i) {
        int row = row0 + ty * 4 + i;
        if (row < N_NODES)
            *(float4*)&out[(size_t)row * D + tx * 4] =
                make_float4(acc[i][0], acc[i][1], acc[i][2], acc[i][3]);
    }
}

extern "C" void kernel_launch(void* const* d_in, const int* in_sizes, int n_in,
                              void* d_out, int out_size, void* d_ws, size_t ws_size,
                              hipStream_t stream) {
    const float* x    = (const float*)d_in[0];
    const int*   esrc = (const int*)  d_in[1];
    const int*   edst = (const int*)  d_in[2];
    const float* ev   = (const float*)d_in[3];
    const float* w    = (const float*)d_in[4];
    const float* eps  = (const float*)d_in[5];
    const float* bias = (const float*)d_in[6];

    float* out = (float*)d_out;
    float* rep = out + (size_t)N_NODES * D;

    int* ws       = (int*)d_ws;
    int* ghist    = ws + WS_GHIST;
    int* partial  = ws + WS_PART;
    int* row_ptr  = ws + WS_ROWPTR;
    unsigned int* pairsu = (unsigned int*)(ws + WS_PAIRSU);
    uint2* xh2    = (uint2*)(ws + WS_XH);
    int2* tpairs  = (int2*)rep;   // consumed by k_build before k_gather writes rep

    k_hist_cvt<<<BLKA, 256, 0, stream>>>(esrc, x, ghist, xh2);
    k_scan1<<<NCH, 1024, 0, stream>>>(ghist, partial);
    k_scan2<<<NCH, 1024, 0, stream>>>(ghist, partial);
    k_scatter<<<BLKA, 256, 0, stream>>>(esrc, edst, ev, ghist, tpairs);
    k_build<<<NB, 256, 0, stream>>>(tpairs, ghist, row_ptr, pairsu);
    k_gather<<<GATHER_BLOCKS, 256, 0, stream>>>(x, xh2, row_ptr, pairsu, eps, rep);
    k_gemm<<<(N_NODES + GEMM_TM - 1) / GEMM_TM, 256, 0, stream>>>(rep, w, bias, out);
}